// Round 16
// baseline (172.882 us; speedup 1.0000x reference)
//
#include <hip/hip_runtime.h>

#define NPTS 4096
#define DIM  256
#define NNB  16
#define NCAND 32            // candidates per row after merge
#define LTOP  8             // per-stream top-L
#define JC    8             // j-chunks (grid.x)
#define JPC   (NPTS / JC)   // 512 j per chunk
#define NSTR  (JC * 4)      // 32 streams per row (chunk x wave)
#define NPART (NSTR * LTOP) // 256 candidates per row pre-merge

using bf16x8 = __attribute__((ext_vector_type(8))) short;
using f32x4  = __attribute__((ext_vector_type(4))) float;

static __device__ __forceinline__ unsigned short f2bf(float f) {
    unsigned u = __float_as_uint(f);
    u += 0x7FFFu + ((u >> 16) & 1u);          // RNE
    return (unsigned short)(u >> 16);
}

// Orderable float bits: monotone u32 mapping of f32 (handles negatives).
static __device__ __forceinline__ unsigned fbits(float k) {
    unsigned u = __float_as_uint(k);
    return u ^ (((unsigned)((int)u >> 31)) | 0x80000000u);
}

#define CSWAP(x, y) { unsigned _lo = ((x) < (y)) ? (x) : (y); \
                      unsigned _hi = ((x) < (y)) ? (y) : (x); \
                      (x) = _lo; (y) = _hi; }

// ---- prep: transpose C[d][p] -> Ct[p][d] (f32) + CbT (bf16) + sq norms ----
__global__ __launch_bounds__(256) void prep_kernel(const float* __restrict__ C,
                                                   float* __restrict__ Ct,
                                                   unsigned short* __restrict__ CbT,
                                                   float* __restrict__ sq) {
    __shared__ float T[64][65];
    __shared__ float sqp[4][64];
    const int t  = threadIdx.x;
    const int p0 = blockIdx.x * 64;
    const int r  = t >> 4;          // 0..15
    const int c4 = (t & 15) * 4;    // 0..60
    const int pp = t & 63;
    const int q  = t >> 6;          // quarter 0..3
    float part = 0.0f;
    for (int d0 = 0; d0 < DIM; d0 += 64) {
        __syncthreads();
        #pragma unroll
        for (int s = 0; s < 4; ++s) {
            int dl = r + s * 16;
            float4 v = *(const float4*)&C[(size_t)(d0 + dl) * NPTS + p0 + c4];
            T[dl][c4 + 0] = v.x; T[dl][c4 + 1] = v.y;
            T[dl][c4 + 2] = v.z; T[dl][c4 + 3] = v.w;
        }
        __syncthreads();
        #pragma unroll
        for (int s = 0; s < 4; ++s) {
            int pl = r + s * 16;
            float4 v;
            v.x = T[c4 + 0][pl]; v.y = T[c4 + 1][pl];
            v.z = T[c4 + 2][pl]; v.w = T[c4 + 3][pl];
            *(float4*)&Ct[(size_t)(p0 + pl) * DIM + d0 + c4] = v;
            unsigned lo = (unsigned)f2bf(v.x) | ((unsigned)f2bf(v.y) << 16);
            unsigned hi = (unsigned)f2bf(v.z) | ((unsigned)f2bf(v.w) << 16);
            *(uint2*)&CbT[(size_t)(p0 + pl) * DIM + d0 + c4] = make_uint2(lo, hi);
        }
        #pragma unroll
        for (int dd = 0; dd < 16; ++dd) {
            float v = T[q * 16 + dd][pp];
            part = fmaf(v, v, part);
        }
    }
    sqp[q][pp] = part;
    __syncthreads();
    if (t < 64)
        sq[p0 + t] = ((sqp[0][t] + sqp[1][t]) + sqp[2][t]) + sqp[3][t];
}

// ---- register-direct gemm+select: wave-split j, cross-lane merged top-8 ----
// grid (JC=8, 256); block 256 = 4 waves; block owns 16 i-rows (i0+lm per lane),
// wave w scans j-quarter [jbase+w*128, ...+128). 8192 waves total -> high TLP.
// Swapped MFMA operands: out col(lane&15)=i, row((lane>>4)*4+reg)=j.
// Key pack: high 20 bits = orderable f32 bits (floored), low 12 bits = j.
// After the scan, per-wave cross-lane bitonic merge (shfl_xor 16, 32) collapses
// the 4 lane-group streams into one sorted top-8 (identical in all 4 lanes).
__global__ __launch_bounds__(256) void gemm_select_kernel(
    const unsigned short* __restrict__ CbT, const float* __restrict__ sq,
    unsigned* __restrict__ parts)
{
    const int t    = threadIdx.x;
    const int wave = t >> 6, lane = t & 63;
    const int i0   = blockIdx.y * 16;
    const int jbase = blockIdx.x * JPC + wave * (JPC / 4);   // 128-j quarter
    const int lm   = lane & 15;
    const int g    = lane >> 4;          // group 0..3
    const int kg   = g * 8;              // k-offset within a 32-k step

    bf16x8 bfr[8];
    #pragma unroll
    for (int k0 = 0; k0 < 8; ++k0)
        bfr[k0] = *(const bf16x8*)&CbT[(size_t)(i0 + lm) * DIM + k0 * 32 + kg];

    unsigned kk[LTOP];
    #pragma unroll
    for (int p = 0; p < LTOP; ++p) kk[p] = 0xFFFFFFFFu;

    for (int jt = 0; jt < JPC / 4 / 32; ++jt) {   // 4 iters, 2 tiles (32 j) each
        const int jA = jbase + jt * 32;
        const int jB = jA + 16;
        bf16x8 aA[8], aB[8];
        #pragma unroll
        for (int k0 = 0; k0 < 8; ++k0) {
            aA[k0] = *(const bf16x8*)&CbT[(size_t)(jA + lm) * DIM + k0 * 32 + kg];
            aB[k0] = *(const bf16x8*)&CbT[(size_t)(jB + lm) * DIM + k0 * 32 + kg];
        }
        f32x4 accA0 = {}, accA1 = {}, accB0 = {}, accB1 = {};
        #pragma unroll
        for (int k0 = 0; k0 < 8; k0 += 2) {       // 4 independent chains
            accA0 = __builtin_amdgcn_mfma_f32_16x16x32_bf16(aA[k0],     bfr[k0],     accA0, 0, 0, 0);
            accA1 = __builtin_amdgcn_mfma_f32_16x16x32_bf16(aA[k0 + 1], bfr[k0 + 1], accA1, 0, 0, 0);
            accB0 = __builtin_amdgcn_mfma_f32_16x16x32_bf16(aB[k0],     bfr[k0],     accB0, 0, 0, 0);
            accB1 = __builtin_amdgcn_mfma_f32_16x16x32_bf16(aB[k0 + 1], bfr[k0 + 1], accB1, 0, 0, 0);
        }
        float4 sjA = *(const float4*)&sq[jA + g * 4];
        float4 sjB = *(const float4*)&sq[jB + g * 4];
        unsigned c[8];
        #pragma unroll
        for (int r = 0; r < 4; ++r) {
            float sa = (r == 0) ? sjA.x : (r == 1) ? sjA.y : (r == 2) ? sjA.z : sjA.w;
            float sb = (r == 0) ? sjB.x : (r == 1) ? sjB.y : (r == 2) ? sjB.z : sjB.w;
            float kA = fmaf(-2.0f, accA0[r] + accA1[r], sa);
            float kB = fmaf(-2.0f, accB0[r] + accB1[r], sb);
            c[r]     = (fbits(kA) & 0xFFFFF000u) | (unsigned)(jA + g * 4 + r);
            c[4 + r] = (fbits(kB) & 0xFFFFF000u) | (unsigned)(jB + g * 4 + r);
        }
        // Batcher odd-even sort-8 (19 comparators)
        CSWAP(c[0], c[1]); CSWAP(c[2], c[3]); CSWAP(c[4], c[5]); CSWAP(c[6], c[7]);
        CSWAP(c[0], c[2]); CSWAP(c[1], c[3]); CSWAP(c[4], c[6]); CSWAP(c[5], c[7]);
        CSWAP(c[1], c[2]); CSWAP(c[5], c[6]);
        CSWAP(c[0], c[4]); CSWAP(c[1], c[5]); CSWAP(c[2], c[6]); CSWAP(c[3], c[7]);
        CSWAP(c[2], c[4]); CSWAP(c[3], c[5]);
        CSWAP(c[1], c[2]); CSWAP(c[3], c[4]); CSWAP(c[5], c[6]);
        // half-cleaner vs running top-8 + bitonic clean
        unsigned m[8];
        #pragma unroll
        for (int i = 0; i < 8; ++i)
            m[i] = (kk[i] < c[7 - i]) ? kk[i] : c[7 - i];
        CSWAP(m[0], m[4]); CSWAP(m[1], m[5]); CSWAP(m[2], m[6]); CSWAP(m[3], m[7]);
        CSWAP(m[0], m[2]); CSWAP(m[1], m[3]); CSWAP(m[4], m[6]); CSWAP(m[5], m[7]);
        CSWAP(m[0], m[1]); CSWAP(m[2], m[3]); CSWAP(m[4], m[5]); CSWAP(m[6], m[7]);
        #pragma unroll
        for (int i = 0; i < 8; ++i) kk[i] = m[i];
    }

    // cross-lane merge: combine the 4 lane-group streams (same i = lm) into
    // one top-8.  Round 1: lane^16; Round 2: lane^32.  Both partners compute
    // the identical union-bottom-8 (min(a[i], b[7-i]) + bitonic clean).
    #pragma unroll
    for (int round = 0; round < 2; ++round) {
        const int dx = (round == 0) ? 16 : 32;
        unsigned pb[8], m[8];
        #pragma unroll
        for (int i = 0; i < 8; ++i)
            pb[i] = (unsigned)__shfl_xor((int)kk[i], dx);
        #pragma unroll
        for (int i = 0; i < 8; ++i)
            m[i] = (kk[i] < pb[7 - i]) ? kk[i] : pb[7 - i];
        CSWAP(m[0], m[4]); CSWAP(m[1], m[5]); CSWAP(m[2], m[6]); CSWAP(m[3], m[7]);
        CSWAP(m[0], m[2]); CSWAP(m[1], m[3]); CSWAP(m[4], m[6]); CSWAP(m[5], m[7]);
        CSWAP(m[0], m[1]); CSWAP(m[2], m[3]); CSWAP(m[4], m[5]); CSWAP(m[6], m[7]);
        #pragma unroll
        for (int i = 0; i < 8; ++i) kk[i] = m[i];
    }

    if (g == 0) {
        const int row = i0 + lm;
        unsigned* dst = &parts[((size_t)row * NSTR + blockIdx.x * 4 + wave) * LTOP];
        #pragma unroll
        for (int p = 0; p < LTOP; ++p) dst[p] = kk[p];
    }
}

// ---- fused merge (256 parts -> top-32) + exact f64 refine -> fidx ----
__global__ __launch_bounds__(NPART) void merge_refine_kernel(
    const unsigned* __restrict__ parts, const float* __restrict__ Ct,
    int* __restrict__ fidx)
{
    __shared__ unsigned e[NPART];
    __shared__ float  xi[DIM];
    __shared__ int    cidx[NCAND];
    __shared__ double pd[NCAND][8];
    __shared__ double sums[NCAND];
    const int row = blockIdx.x;
    const int t   = threadIdx.x;

    unsigned mine = parts[(size_t)row * NPART + t];
    e[t] = mine;
    if (t < 64) *(float4*)&xi[t * 4] = *(const float4*)&Ct[(size_t)row * DIM + t * 4];
    __syncthreads();
    int rank = 0;
    for (int o = 0; o < NPART; ++o) rank += e[o] < mine;   // distinct (j unique)
    if (rank < NCAND) cidx[rank] = (int)(mine & 0xFFFu);
    __syncthreads();

    if (t < NCAND * 8) {                 // 8 threads per candidate, 32 dims each
        const int c = t >> 3, sl = t & 7;
        const int j = cidx[c];
        const float* xj = &Ct[(size_t)j * DIM];
        double s = 0.0;
        for (int d = sl * 32; d < sl * 32 + 32; d += 4) {
            float4 v = *(const float4*)&xj[d];
            double e0 = (double)xi[d + 0] - (double)v.x; s = fma(e0, e0, s);
            double e1 = (double)xi[d + 1] - (double)v.y; s = fma(e1, e1, s);
            double e2 = (double)xi[d + 2] - (double)v.z; s = fma(e2, e2, s);
            double e3 = (double)xi[d + 3] - (double)v.w; s = fma(e3, e3, s);
        }
        pd[c][sl] = s;
    }
    __syncthreads();
    if (t < NCAND) {
        double s = 0.0;
        #pragma unroll
        for (int sl = 0; sl < 8; ++sl) s += pd[t][sl];   // fixed order: deterministic
        sums[t] = s;
    }
    __syncthreads();
    if (t < NCAND) {
        double s = sums[t]; int j = cidx[t];
        int rk = 0;
        #pragma unroll
        for (int o = 0; o < NCAND; ++o) {
            double os = sums[o]; int oj = cidx[o];
            rk += (os < s) || (os == s && oj < j);
        }
        if (rk < NNB) fidx[row * NNB + rk] = j;
    }
}

// ---- gather: 2 slices x 1280 rows; fidx reg-prefetch; plain stores ----
__global__ __launch_bounds__(256) void gather_all_kernel(const float* __restrict__ xs,
                                                         const float* __restrict__ coords,
                                                         const int* __restrict__ fidx,
                                                         float* __restrict__ out) {
    __shared__ float row[NPTS];
    const int rb    = blockIdx.y;
    const int slice = blockIdx.x;          // 0..1, 32768 cols each
    const int t     = threadIdx.x;
    const float* srow;
    float* drow;
    if (rb < 1024) { srow = xs + (size_t)rb * NPTS;            drow = out + (size_t)rb * 65536; }
    else           { srow = coords + (size_t)(rb - 1024) * NPTS;
                     drow = out + (size_t)1024 * 65536 + (size_t)(rb - 1024) * 65536; }
    const int cbase = slice * 32768;

    int4 ids[8];
    #pragma unroll
    for (int q = 0; q < 8; ++q)
        ids[q] = *(const int4*)&fidx[cbase + (q * 256 + t) * 4];

    #pragma unroll
    for (int s = 0; s < NPTS / 1024; ++s)
        *(float4*)&row[(s * 256 + t) * 4] = *(const float4*)&srow[(s * 256 + t) * 4];
    __syncthreads();

    for (int g = 0; g < 4; ++g) {
        int4 nxt[8];
        if (g < 3) {
            #pragma unroll
            for (int q = 0; q < 8; ++q)
                nxt[q] = *(const int4*)&fidx[cbase + ((g + 1) * 2048 + q * 256 + t) * 4];
        }
        #pragma unroll
        for (int q = 0; q < 8; ++q) {
            int c4 = cbase + (g * 2048 + q * 256 + t) * 4;
            int4 id = ids[q];
            f32x4 v;
            v[0] = row[id.x]; v[1] = row[id.y]; v[2] = row[id.z]; v[3] = row[id.w];
            *(f32x4*)&drow[c4] = v;
        }
        #pragma unroll
        for (int q = 0; q < 8; ++q) ids[q] = nxt[q];
    }
}

extern "C" void kernel_launch(void* const* d_in, const int* in_sizes, int n_in,
                              void* d_out, int out_size, void* d_ws, size_t ws_size,
                              hipStream_t stream) {
    const float* xs     = (const float*)d_in[0];
    const float* coords = (const float*)d_in[1];
    float* out = (float*)d_out;

    // Scratch in the HEAD of d_out (out0 = 268 MB; all consumed by merge_refine
    // before the gather overwrites). fidx lives in d_ws.
    unsigned*       parts = (unsigned*)out;                        // 4096*256 u32 = 4 MB
    float*          Ct    = out + (size_t)NPTS * NPART;            // 4096*256 f32
    unsigned short* CbT   = (unsigned short*)(Ct + (size_t)NPTS * DIM);
    float*          sqv   = (float*)(CbT + (size_t)NPTS * DIM);    // 4096 f32
    int*            fidx  = (int*)d_ws;                            // 4096*16 i32

    prep_kernel<<<64, 256, 0, stream>>>(coords, Ct, CbT, sqv);
    gemm_select_kernel<<<dim3(JC, 256), 256, 0, stream>>>(CbT, sqv, parts);
    merge_refine_kernel<<<NPTS, NPART, 0, stream>>>(parts, Ct, fidx);
    gather_all_kernel<<<dim3(2, 1280), 256, 0, stream>>>(xs, coords, fidx, out);
}

// Round 19
// 159.635 us; speedup vs baseline: 1.0830x; 1.0830x over previous
//
#include <hip/hip_runtime.h>

#define NPTS 4096
#define DIM  256
#define NNB  16
#define NCAND 32            // candidates per row after merge
#define LTOP  8             // per-stream top-L
#define JC    8             // j-chunks (grid.x)
#define JPC   (NPTS / JC)   // 512 j per chunk
#define NSTR  (JC * 4)      // 32 streams per row (chunk x lane-group)
#define NPART (NSTR * LTOP) // 256 candidates per row pre-merge

using bf16x8 = __attribute__((ext_vector_type(8))) short;
using f32x4  = __attribute__((ext_vector_type(4))) float;

static __device__ __forceinline__ unsigned short f2bf(float f) {
    unsigned u = __float_as_uint(f);
    u += 0x7FFFu + ((u >> 16) & 1u);          // RNE
    return (unsigned short)(u >> 16);
}

// Orderable float bits: monotone u32 mapping of f32 (handles negatives).
static __device__ __forceinline__ unsigned fbits(float k) {
    unsigned u = __float_as_uint(k);
    return u ^ (((unsigned)((int)u >> 31)) | 0x80000000u);
}

#define CSWAP(x, y) { unsigned _lo = ((x) < (y)) ? (x) : (y); \
                      unsigned _hi = ((x) < (y)) ? (y) : (x); \
                      (x) = _lo; (y) = _hi; }

// ---- prep: transpose C[d][p] -> Ct[p][d] (f32) + CbT (bf16) + sq norms ----
__global__ __launch_bounds__(256) void prep_kernel(const float* __restrict__ C,
                                                   float* __restrict__ Ct,
                                                   unsigned short* __restrict__ CbT,
                                                   float* __restrict__ sq) {
    __shared__ float T[64][65];
    __shared__ float sqp[4][64];
    const int t  = threadIdx.x;
    const int p0 = blockIdx.x * 64;
    const int r  = t >> 4;          // 0..15
    const int c4 = (t & 15) * 4;    // 0..60
    const int pp = t & 63;
    const int q  = t >> 6;          // quarter 0..3
    float part = 0.0f;
    for (int d0 = 0; d0 < DIM; d0 += 64) {
        __syncthreads();
        #pragma unroll
        for (int s = 0; s < 4; ++s) {
            int dl = r + s * 16;
            float4 v = *(const float4*)&C[(size_t)(d0 + dl) * NPTS + p0 + c4];
            T[dl][c4 + 0] = v.x; T[dl][c4 + 1] = v.y;
            T[dl][c4 + 2] = v.z; T[dl][c4 + 3] = v.w;
        }
        __syncthreads();
        #pragma unroll
        for (int s = 0; s < 4; ++s) {
            int pl = r + s * 16;
            float4 v;
            v.x = T[c4 + 0][pl]; v.y = T[c4 + 1][pl];
            v.z = T[c4 + 2][pl]; v.w = T[c4 + 3][pl];
            *(float4*)&Ct[(size_t)(p0 + pl) * DIM + d0 + c4] = v;
            unsigned lo = (unsigned)f2bf(v.x) | ((unsigned)f2bf(v.y) << 16);
            unsigned hi = (unsigned)f2bf(v.z) | ((unsigned)f2bf(v.w) << 16);
            *(uint2*)&CbT[(size_t)(p0 + pl) * DIM + d0 + c4] = make_uint2(lo, hi);
        }
        #pragma unroll
        for (int dd = 0; dd < 16; ++dd) {
            float v = T[q * 16 + dd][pp];
            part = fmaf(v, v, part);
        }
    }
    sqp[q][pp] = part;
    __syncthreads();
    if (t < 64)
        sq[p0 + t] = ((sqp[0][t] + sqp[1][t]) + sqp[2][t]) + sqp[3][t];
}

// ---- register-direct gemm+select: 2-tile ILP + sorting-network top-8 ----
// grid (JC=8, 64); block 256 = 4 waves; wave owns 16 i-rows (i0+lm per lane).
// Swapped MFMA operands: out col(lane&15)=i, row((lane>>4)*4+reg)=j.
// Key pack: high 20 bits = orderable f32 bits (floored), low 12 bits = j.
// Quantization (<=0.12 on d^2) << rank margin (~10); exact refine downstream.
__global__ __launch_bounds__(256) void gemm_select_kernel(
    const unsigned short* __restrict__ CbT, const float* __restrict__ sq,
    unsigned* __restrict__ parts)
{
    const int t    = threadIdx.x;
    const int wave = t >> 6, lane = t & 63;
    const int i0   = blockIdx.y * 64 + wave * 16;
    const int jbase = blockIdx.x * JPC;
    const int lm   = lane & 15;
    const int g    = lane >> 4;          // group 0..3
    const int kg   = g * 8;              // k-offset within a 32-k step

    bf16x8 bfr[8];
    #pragma unroll
    for (int k0 = 0; k0 < 8; ++k0)
        bfr[k0] = *(const bf16x8*)&CbT[(size_t)(i0 + lm) * DIM + k0 * 32 + kg];

    unsigned kk[LTOP];
    #pragma unroll
    for (int p = 0; p < LTOP; ++p) kk[p] = 0xFFFFFFFFu;

    for (int jt = 0; jt < JPC / 32; ++jt) {       // 16 iters, 2 tiles (32 j) each
        const int jA = jbase + jt * 32;
        const int jB = jA + 16;
        // burst-load both tiles' fragments: 16 loads in flight
        bf16x8 aA[8], aB[8];
        #pragma unroll
        for (int k0 = 0; k0 < 8; ++k0) {
            aA[k0] = *(const bf16x8*)&CbT[(size_t)(jA + lm) * DIM + k0 * 32 + kg];
            aB[k0] = *(const bf16x8*)&CbT[(size_t)(jB + lm) * DIM + k0 * 32 + kg];
        }
        f32x4 accA0 = {}, accA1 = {}, accB0 = {}, accB1 = {};
        #pragma unroll
        for (int k0 = 0; k0 < 8; k0 += 2) {       // 4 independent chains
            accA0 = __builtin_amdgcn_mfma_f32_16x16x32_bf16(aA[k0],     bfr[k0],     accA0, 0, 0, 0);
            accA1 = __builtin_amdgcn_mfma_f32_16x16x32_bf16(aA[k0 + 1], bfr[k0 + 1], accA1, 0, 0, 0);
            accB0 = __builtin_amdgcn_mfma_f32_16x16x32_bf16(aB[k0],     bfr[k0],     accB0, 0, 0, 0);
            accB1 = __builtin_amdgcn_mfma_f32_16x16x32_bf16(aB[k0 + 1], bfr[k0 + 1], accB1, 0, 0, 0);
        }
        float4 sjA = *(const float4*)&sq[jA + g * 4];
        float4 sjB = *(const float4*)&sq[jB + g * 4];
        unsigned c[8];
        #pragma unroll
        for (int r = 0; r < 4; ++r) {
            float sa = (r == 0) ? sjA.x : (r == 1) ? sjA.y : (r == 2) ? sjA.z : sjA.w;
            float sb = (r == 0) ? sjB.x : (r == 1) ? sjB.y : (r == 2) ? sjB.z : sjB.w;
            float kA = fmaf(-2.0f, accA0[r] + accA1[r], sa);
            float kB = fmaf(-2.0f, accB0[r] + accB1[r], sb);
            c[r]     = (fbits(kA) & 0xFFFFF000u) | (unsigned)(jA + g * 4 + r);
            c[4 + r] = (fbits(kB) & 0xFFFFF000u) | (unsigned)(jB + g * 4 + r);
        }
        // Batcher odd-even sort-8 (19 comparators, depth 6)
        CSWAP(c[0], c[1]); CSWAP(c[2], c[3]); CSWAP(c[4], c[5]); CSWAP(c[6], c[7]);
        CSWAP(c[0], c[2]); CSWAP(c[1], c[3]); CSWAP(c[4], c[6]); CSWAP(c[5], c[7]);
        CSWAP(c[1], c[2]); CSWAP(c[5], c[6]);
        CSWAP(c[0], c[4]); CSWAP(c[1], c[5]); CSWAP(c[2], c[6]); CSWAP(c[3], c[7]);
        CSWAP(c[2], c[4]); CSWAP(c[3], c[5]);
        CSWAP(c[1], c[2]); CSWAP(c[3], c[4]); CSWAP(c[5], c[6]);
        // half-cleaner vs running top-8 (both ascending) -> bitonic low half
        unsigned m[8];
        #pragma unroll
        for (int i = 0; i < 8; ++i)
            m[i] = (kk[i] < c[7 - i]) ? kk[i] : c[7 - i];
        // bitonic clean (12 comparators, depth 3)
        CSWAP(m[0], m[4]); CSWAP(m[1], m[5]); CSWAP(m[2], m[6]); CSWAP(m[3], m[7]);
        CSWAP(m[0], m[2]); CSWAP(m[1], m[3]); CSWAP(m[4], m[6]); CSWAP(m[5], m[7]);
        CSWAP(m[0], m[1]); CSWAP(m[2], m[3]); CSWAP(m[4], m[5]); CSWAP(m[6], m[7]);
        #pragma unroll
        for (int i = 0; i < 8; ++i) kk[i] = m[i];
    }

    const int row = i0 + lm;
    unsigned* dst = &parts[((size_t)row * NSTR + blockIdx.x * 4 + g) * LTOP];
    #pragma unroll
    for (int p = 0; p < LTOP; ++p) dst[p] = kk[p];
}

// ---- fused merge (256 parts -> top-32) + exact f64 refine -> fidx ----
__global__ __launch_bounds__(NPART) void merge_refine_kernel(
    const unsigned* __restrict__ parts, const float* __restrict__ Ct,
    int* __restrict__ fidx)
{
    __shared__ unsigned e[NPART];
    __shared__ float  xi[DIM];
    __shared__ int    cidx[NCAND];
    __shared__ double pd[NCAND][8];
    __shared__ double sums[NCAND];
    const int row = blockIdx.x;
    const int t   = threadIdx.x;

    unsigned mine = parts[(size_t)row * NPART + t];
    e[t] = mine;
    if (t < 64) *(float4*)&xi[t * 4] = *(const float4*)&Ct[(size_t)row * DIM + t * 4];
    __syncthreads();
    int rank = 0;
    for (int o = 0; o < NPART; ++o) rank += e[o] < mine;   // distinct (j unique)
    if (rank < NCAND) cidx[rank] = (int)(mine & 0xFFFu);
    __syncthreads();

    if (t < NCAND * 8) {                 // 8 threads per candidate, 32 dims each
        const int c = t >> 3, sl = t & 7;
        const int j = cidx[c];
        const float* xj = &Ct[(size_t)j * DIM];
        double s = 0.0;
        for (int d = sl * 32; d < sl * 32 + 32; d += 4) {
            float4 v = *(const float4*)&xj[d];
            double e0 = (double)xi[d + 0] - (double)v.x; s = fma(e0, e0, s);
            double e1 = (double)xi[d + 1] - (double)v.y; s = fma(e1, e1, s);
            double e2 = (double)xi[d + 2] - (double)v.z; s = fma(e2, e2, s);
            double e3 = (double)xi[d + 3] - (double)v.w; s = fma(e3, e3, s);
        }
        pd[c][sl] = s;
    }
    __syncthreads();
    if (t < NCAND) {
        double s = 0.0;
        #pragma unroll
        for (int sl = 0; sl < 8; ++sl) s += pd[t][sl];   // fixed order: deterministic
        sums[t] = s;
    }
    __syncthreads();
    if (t < NCAND) {
        double s = sums[t]; int j = cidx[t];
        int rk = 0;
        #pragma unroll
        for (int o = 0; o < NCAND; ++o) {
            double os = sums[o]; int oj = cidx[o];
            rk += (os < s) || (os == s && oj < j);
        }
        if (rk < NNB) fidx[row * NNB + rk] = j;
    }
}

// ---- gather: 2 slices x 1280 rows; fidx reg-prefetch; plain stores ----
__global__ __launch_bounds__(256) void gather_all_kernel(const float* __restrict__ xs,
                                                         const float* __restrict__ coords,
                                                         const int* __restrict__ fidx,
                                                         float* __restrict__ out) {
    __shared__ float row[NPTS];
    const int rb    = blockIdx.y;
    const int slice = blockIdx.x;          // 0..1, 32768 cols each
    const int t     = threadIdx.x;
    const float* srow;
    float* drow;
    if (rb < 1024) { srow = xs + (size_t)rb * NPTS;            drow = out + (size_t)rb * 65536; }
    else           { srow = coords + (size_t)(rb - 1024) * NPTS;
                     drow = out + (size_t)1024 * 65536 + (size_t)(rb - 1024) * 65536; }
    const int cbase = slice * 32768;

    int4 ids[8];
    #pragma unroll
    for (int q = 0; q < 8; ++q)
        ids[q] = *(const int4*)&fidx[cbase + (q * 256 + t) * 4];

    #pragma unroll
    for (int s = 0; s < NPTS / 1024; ++s)
        *(float4*)&row[(s * 256 + t) * 4] = *(const float4*)&srow[(s * 256 + t) * 4];
    __syncthreads();

    for (int g = 0; g < 4; ++g) {
        int4 nxt[8];
        if (g < 3) {
            #pragma unroll
            for (int q = 0; q < 8; ++q)
                nxt[q] = *(const int4*)&fidx[cbase + ((g + 1) * 2048 + q * 256 + t) * 4];
        }
        #pragma unroll
        for (int q = 0; q < 8; ++q) {
            int c4 = cbase + (g * 2048 + q * 256 + t) * 4;
            int4 id = ids[q];
            f32x4 v;
            v[0] = row[id.x]; v[1] = row[id.y]; v[2] = row[id.z]; v[3] = row[id.w];
            *(f32x4*)&drow[c4] = v;
        }
        #pragma unroll
        for (int q = 0; q < 8; ++q) ids[q] = nxt[q];
    }
}

extern "C" void kernel_launch(void* const* d_in, const int* in_sizes, int n_in,
                              void* d_out, int out_size, void* d_ws, size_t ws_size,
                              hipStream_t stream) {
    const float* xs     = (const float*)d_in[0];
    const float* coords = (const float*)d_in[1];
    float* out = (float*)d_out;

    // Scratch in the HEAD of d_out (out0 = 268 MB; all consumed by merge_refine
    // before the gather overwrites). fidx lives in d_ws.
    unsigned*       parts = (unsigned*)out;                        // 4096*256 u32 = 4 MB
    float*          Ct    = out + (size_t)NPTS * NPART;            // 4096*256 f32
    unsigned short* CbT   = (unsigned short*)(Ct + (size_t)NPTS * DIM);
    float*          sqv   = (float*)(CbT + (size_t)NPTS * DIM);    // 4096 f32
    int*            fidx  = (int*)d_ws;                            // 4096*16 i32

    prep_kernel<<<64, 256, 0, stream>>>(coords, Ct, CbT, sqv);
    gemm_select_kernel<<<dim3(JC, 64), 256, 0, stream>>>(CbT, sqv, parts);
    merge_refine_kernel<<<NPTS, NPART, 0, stream>>>(parts, Ct, fidx);
    gather_all_kernel<<<dim3(2, 1280), 256, 0, stream>>>(xs, coords, fidx, out);
}

// Round 20
// 159.254 us; speedup vs baseline: 1.0856x; 1.0024x over previous
//
#include <hip/hip_runtime.h>

#define NPTS 4096
#define DIM  256
#define NNB  16
#define NCAND 32            // candidates per row after merge
#define LTOP  8             // per-stream top-L
#define JC    8             // j-chunks (grid.x)
#define JPC   (NPTS / JC)   // 512 j per chunk
#define NSTR  (JC * 4)      // 32 streams per row (chunk x lane-group)
#define NPART (NSTR * LTOP) // 256 candidates per row pre-merge

using bf16x8 = __attribute__((ext_vector_type(8))) short;
using f32x4  = __attribute__((ext_vector_type(4))) float;
using u16x4  = __attribute__((ext_vector_type(4))) unsigned short;

static __device__ __forceinline__ unsigned short f2bf(float f) {
    unsigned u = __float_as_uint(f);
    u += 0x7FFFu + ((u >> 16) & 1u);          // RNE
    return (unsigned short)(u >> 16);
}

// Orderable float bits: monotone u32 mapping of f32 (handles negatives).
static __device__ __forceinline__ unsigned fbits(float k) {
    unsigned u = __float_as_uint(k);
    return u ^ (((unsigned)((int)u >> 31)) | 0x80000000u);
}

#define CSWAP(x, y) { unsigned _lo = ((x) < (y)) ? (x) : (y); \
                      unsigned _hi = ((x) < (y)) ? (y) : (x); \
                      (x) = _lo; (y) = _hi; }

// ---- prep: transpose C[d][p] -> Ct[p][d] (f32) + CbT (bf16) + sq norms ----
__global__ __launch_bounds__(256) void prep_kernel(const float* __restrict__ C,
                                                   float* __restrict__ Ct,
                                                   unsigned short* __restrict__ CbT,
                                                   float* __restrict__ sq) {
    __shared__ float T[64][65];
    __shared__ float sqp[4][64];
    const int t  = threadIdx.x;
    const int p0 = blockIdx.x * 64;
    const int r  = t >> 4;          // 0..15
    const int c4 = (t & 15) * 4;    // 0..60
    const int pp = t & 63;
    const int q  = t >> 6;          // quarter 0..3
    float part = 0.0f;
    for (int d0 = 0; d0 < DIM; d0 += 64) {
        __syncthreads();
        #pragma unroll
        for (int s = 0; s < 4; ++s) {
            int dl = r + s * 16;
            float4 v = *(const float4*)&C[(size_t)(d0 + dl) * NPTS + p0 + c4];
            T[dl][c4 + 0] = v.x; T[dl][c4 + 1] = v.y;
            T[dl][c4 + 2] = v.z; T[dl][c4 + 3] = v.w;
        }
        __syncthreads();
        #pragma unroll
        for (int s = 0; s < 4; ++s) {
            int pl = r + s * 16;
            float4 v;
            v.x = T[c4 + 0][pl]; v.y = T[c4 + 1][pl];
            v.z = T[c4 + 2][pl]; v.w = T[c4 + 3][pl];
            *(float4*)&Ct[(size_t)(p0 + pl) * DIM + d0 + c4] = v;
            unsigned lo = (unsigned)f2bf(v.x) | ((unsigned)f2bf(v.y) << 16);
            unsigned hi = (unsigned)f2bf(v.z) | ((unsigned)f2bf(v.w) << 16);
            *(uint2*)&CbT[(size_t)(p0 + pl) * DIM + d0 + c4] = make_uint2(lo, hi);
        }
        #pragma unroll
        for (int dd = 0; dd < 16; ++dd) {
            float v = T[q * 16 + dd][pp];
            part = fmaf(v, v, part);
        }
    }
    sqp[q][pp] = part;
    __syncthreads();
    if (t < 64)
        sq[p0 + t] = ((sqp[0][t] + sqp[1][t]) + sqp[2][t]) + sqp[3][t];
}

// ---- register-direct gemm+select: 2-tile ILP + sorting-network top-8 ----
// grid (JC=8, 64); block 256 = 4 waves; wave owns 16 i-rows (i0+lm per lane).
// Swapped MFMA operands: out col(lane&15)=i, row((lane>>4)*4+reg)=j.
// Key pack: high 20 bits = orderable f32 bits (floored), low 12 bits = j.
// Quantization (<=0.12 on d^2) << rank margin (~10); exact refine downstream.
__global__ __launch_bounds__(256) void gemm_select_kernel(
    const unsigned short* __restrict__ CbT, const float* __restrict__ sq,
    unsigned* __restrict__ parts)
{
    const int t    = threadIdx.x;
    const int wave = t >> 6, lane = t & 63;
    const int i0   = blockIdx.y * 64 + wave * 16;
    const int jbase = blockIdx.x * JPC;
    const int lm   = lane & 15;
    const int g    = lane >> 4;          // group 0..3
    const int kg   = g * 8;              // k-offset within a 32-k step

    bf16x8 bfr[8];
    #pragma unroll
    for (int k0 = 0; k0 < 8; ++k0)
        bfr[k0] = *(const bf16x8*)&CbT[(size_t)(i0 + lm) * DIM + k0 * 32 + kg];

    unsigned kk[LTOP];
    #pragma unroll
    for (int p = 0; p < LTOP; ++p) kk[p] = 0xFFFFFFFFu;

    for (int jt = 0; jt < JPC / 32; ++jt) {       // 16 iters, 2 tiles (32 j) each
        const int jA = jbase + jt * 32;
        const int jB = jA + 16;
        // burst-load both tiles' fragments: 16 loads in flight
        bf16x8 aA[8], aB[8];
        #pragma unroll
        for (int k0 = 0; k0 < 8; ++k0) {
            aA[k0] = *(const bf16x8*)&CbT[(size_t)(jA + lm) * DIM + k0 * 32 + kg];
            aB[k0] = *(const bf16x8*)&CbT[(size_t)(jB + lm) * DIM + k0 * 32 + kg];
        }
        f32x4 accA0 = {}, accA1 = {}, accB0 = {}, accB1 = {};
        #pragma unroll
        for (int k0 = 0; k0 < 8; k0 += 2) {       // 4 independent chains
            accA0 = __builtin_amdgcn_mfma_f32_16x16x32_bf16(aA[k0],     bfr[k0],     accA0, 0, 0, 0);
            accA1 = __builtin_amdgcn_mfma_f32_16x16x32_bf16(aA[k0 + 1], bfr[k0 + 1], accA1, 0, 0, 0);
            accB0 = __builtin_amdgcn_mfma_f32_16x16x32_bf16(aB[k0],     bfr[k0],     accB0, 0, 0, 0);
            accB1 = __builtin_amdgcn_mfma_f32_16x16x32_bf16(aB[k0 + 1], bfr[k0 + 1], accB1, 0, 0, 0);
        }
        float4 sjA = *(const float4*)&sq[jA + g * 4];
        float4 sjB = *(const float4*)&sq[jB + g * 4];
        unsigned c[8];
        #pragma unroll
        for (int r = 0; r < 4; ++r) {
            float sa = (r == 0) ? sjA.x : (r == 1) ? sjA.y : (r == 2) ? sjA.z : sjA.w;
            float sb = (r == 0) ? sjB.x : (r == 1) ? sjB.y : (r == 2) ? sjB.z : sjB.w;
            float kA = fmaf(-2.0f, accA0[r] + accA1[r], sa);
            float kB = fmaf(-2.0f, accB0[r] + accB1[r], sb);
            c[r]     = (fbits(kA) & 0xFFFFF000u) | (unsigned)(jA + g * 4 + r);
            c[4 + r] = (fbits(kB) & 0xFFFFF000u) | (unsigned)(jB + g * 4 + r);
        }
        // Batcher odd-even sort-8 (19 comparators, depth 6)
        CSWAP(c[0], c[1]); CSWAP(c[2], c[3]); CSWAP(c[4], c[5]); CSWAP(c[6], c[7]);
        CSWAP(c[0], c[2]); CSWAP(c[1], c[3]); CSWAP(c[4], c[6]); CSWAP(c[5], c[7]);
        CSWAP(c[1], c[2]); CSWAP(c[5], c[6]);
        CSWAP(c[0], c[4]); CSWAP(c[1], c[5]); CSWAP(c[2], c[6]); CSWAP(c[3], c[7]);
        CSWAP(c[2], c[4]); CSWAP(c[3], c[5]);
        CSWAP(c[1], c[2]); CSWAP(c[3], c[4]); CSWAP(c[5], c[6]);
        // half-cleaner vs running top-8 (both ascending) -> bitonic low half
        unsigned m[8];
        #pragma unroll
        for (int i = 0; i < 8; ++i)
            m[i] = (kk[i] < c[7 - i]) ? kk[i] : c[7 - i];
        // bitonic clean (12 comparators, depth 3)
        CSWAP(m[0], m[4]); CSWAP(m[1], m[5]); CSWAP(m[2], m[6]); CSWAP(m[3], m[7]);
        CSWAP(m[0], m[2]); CSWAP(m[1], m[3]); CSWAP(m[4], m[6]); CSWAP(m[5], m[7]);
        CSWAP(m[0], m[1]); CSWAP(m[2], m[3]); CSWAP(m[4], m[5]); CSWAP(m[6], m[7]);
        #pragma unroll
        for (int i = 0; i < 8; ++i) kk[i] = m[i];
    }

    const int row = i0 + lm;
    unsigned* dst = &parts[((size_t)row * NSTR + blockIdx.x * 4 + g) * LTOP];
    #pragma unroll
    for (int p = 0; p < LTOP; ++p) dst[p] = kk[p];
}

// ---- fused merge (256 parts -> top-32) + exact f64 refine -> fidx (u16) ----
__global__ __launch_bounds__(NPART) void merge_refine_kernel(
    const unsigned* __restrict__ parts, const float* __restrict__ Ct,
    unsigned short* __restrict__ fidx)
{
    __shared__ unsigned e[NPART];
    __shared__ float  xi[DIM];
    __shared__ int    cidx[NCAND];
    __shared__ double pd[NCAND][8];
    __shared__ double sums[NCAND];
    const int row = blockIdx.x;
    const int t   = threadIdx.x;

    unsigned mine = parts[(size_t)row * NPART + t];
    e[t] = mine;
    if (t < 64) *(float4*)&xi[t * 4] = *(const float4*)&Ct[(size_t)row * DIM + t * 4];
    __syncthreads();
    int rank = 0;
    for (int o = 0; o < NPART; ++o) rank += e[o] < mine;   // distinct (j unique)
    if (rank < NCAND) cidx[rank] = (int)(mine & 0xFFFu);
    __syncthreads();

    if (t < NCAND * 8) {                 // 8 threads per candidate, 32 dims each
        const int c = t >> 3, sl = t & 7;
        const int j = cidx[c];
        const float* xj = &Ct[(size_t)j * DIM];
        double s = 0.0;
        for (int d = sl * 32; d < sl * 32 + 32; d += 4) {
            float4 v = *(const float4*)&xj[d];
            double e0 = (double)xi[d + 0] - (double)v.x; s = fma(e0, e0, s);
            double e1 = (double)xi[d + 1] - (double)v.y; s = fma(e1, e1, s);
            double e2 = (double)xi[d + 2] - (double)v.z; s = fma(e2, e2, s);
            double e3 = (double)xi[d + 3] - (double)v.w; s = fma(e3, e3, s);
        }
        pd[c][sl] = s;
    }
    __syncthreads();
    if (t < NCAND) {
        double s = 0.0;
        #pragma unroll
        for (int sl = 0; sl < 8; ++sl) s += pd[t][sl];   // fixed order: deterministic
        sums[t] = s;
    }
    __syncthreads();
    if (t < NCAND) {
        double s = sums[t]; int j = cidx[t];
        int rk = 0;
        #pragma unroll
        for (int o = 0; o < NCAND; ++o) {
            double os = sums[o]; int oj = cidx[o];
            rk += (os < s) || (os == s && oj < j);
        }
        if (rk < NNB) fidx[row * NNB + rk] = (unsigned short)j;
    }
}

// ---- gather: 2 slices x 1280 rows; u16 fidx reg-prefetch; plain stores ----
__global__ __launch_bounds__(256) void gather_all_kernel(const float* __restrict__ xs,
                                                         const float* __restrict__ coords,
                                                         const unsigned short* __restrict__ fidx,
                                                         float* __restrict__ out) {
    __shared__ float row[NPTS];
    const int rb    = blockIdx.y;
    const int slice = blockIdx.x;          // 0..1, 32768 cols each
    const int t     = threadIdx.x;
    const float* srow;
    float* drow;
    if (rb < 1024) { srow = xs + (size_t)rb * NPTS;            drow = out + (size_t)rb * 65536; }
    else           { srow = coords + (size_t)(rb - 1024) * NPTS;
                     drow = out + (size_t)1024 * 65536 + (size_t)(rb - 1024) * 65536; }
    const int cbase = slice * 32768;

    u16x4 ids[8];
    #pragma unroll
    for (int q = 0; q < 8; ++q)
        ids[q] = *(const u16x4*)&fidx[cbase + (q * 256 + t) * 4];

    #pragma unroll
    for (int s = 0; s < NPTS / 1024; ++s)
        *(float4*)&row[(s * 256 + t) * 4] = *(const float4*)&srow[(s * 256 + t) * 4];
    __syncthreads();

    for (int g = 0; g < 4; ++g) {
        u16x4 nxt[8];
        if (g < 3) {
            #pragma unroll
            for (int q = 0; q < 8; ++q)
                nxt[q] = *(const u16x4*)&fidx[cbase + ((g + 1) * 2048 + q * 256 + t) * 4];
        }
        #pragma unroll
        for (int q = 0; q < 8; ++q) {
            int c4 = cbase + (g * 2048 + q * 256 + t) * 4;
            u16x4 id = ids[q];
            f32x4 v;
            v[0] = row[id[0]]; v[1] = row[id[1]]; v[2] = row[id[2]]; v[3] = row[id[3]];
            *(f32x4*)&drow[c4] = v;
        }
        #pragma unroll
        for (int q = 0; q < 8; ++q) ids[q] = nxt[q];
    }
}

extern "C" void kernel_launch(void* const* d_in, const int* in_sizes, int n_in,
                              void* d_out, int out_size, void* d_ws, size_t ws_size,
                              hipStream_t stream) {
    const float* xs     = (const float*)d_in[0];
    const float* coords = (const float*)d_in[1];
    float* out = (float*)d_out;

    // Scratch in the HEAD of d_out (out0 = 268 MB; all consumed by merge_refine
    // before the gather overwrites). fidx (u16, 128 KB) lives in d_ws.
    unsigned*       parts = (unsigned*)out;                        // 4096*256 u32 = 4 MB
    float*          Ct    = out + (size_t)NPTS * NPART;            // 4096*256 f32
    unsigned short* CbT   = (unsigned short*)(Ct + (size_t)NPTS * DIM);
    float*          sqv   = (float*)(CbT + (size_t)NPTS * DIM);    // 4096 f32
    unsigned short* fidx  = (unsigned short*)d_ws;                 // 4096*16 u16

    prep_kernel<<<64, 256, 0, stream>>>(coords, Ct, CbT, sqv);
    gemm_select_kernel<<<dim3(JC, 64), 256, 0, stream>>>(CbT, sqv, parts);
    merge_refine_kernel<<<NPTS, NPART, 0, stream>>>(parts, Ct, fidx);
    gather_all_kernel<<<dim3(2, 1280), 256, 0, stream>>>(xs, coords, fidx, out);
}